// Round 20
// baseline (220.673 us; speedup 1.0000x reference)
//
#include <hip/hip_runtime.h>

typedef __bf16 bf16x8 __attribute__((ext_vector_type(8)));
typedef float f32x4 __attribute__((ext_vector_type(4)));
using u16 = unsigned short;

#define SCALE2 (0.17677669529663689f * 1.4426950408889634f)  // 32^-0.5 * log2(e)
#define XROW 528                    // padded LDS row stride (264 u16)
#define FROW 260                    // padded f32 LDS row stride (floats)

// Native bf16 casts (RTNE) -> compiler fuses pairs into v_cvt_pk_bf16_f32.
__device__ __forceinline__ u16 f2bf(float f) {
    union { __bf16 h; u16 u; } x; x.h = (__bf16)f; return x.u;
}
__device__ __forceinline__ unsigned pk2(float a, float b) {
    union { struct { __bf16 lo, hi; } s; unsigned u; } x;
    x.s.lo = (__bf16)a; x.s.hi = (__bf16)b; return x.u;
}
__device__ __forceinline__ float bf2f(u16 h) {
    union { unsigned u; float f; } x; x.u = ((unsigned)h) << 16; return x.f;
}
// gelu = x * sigmoid(1.5957691*(x+0.044715x^3)); exp folded to native exp2
__device__ __forceinline__ float gelu_s(float x) {
    float u = 2.3022150048054216f * x * (1.f + 0.044715f * x * x); // *log2(e)
    float e = exp2f(-u);
    return x / (1.f + e);
}

// ---------------------------------------------------------------- prep ------
__global__ __launch_bounds__(256) void prep_k(
    const float* __restrict__ q_w, const float* __restrict__ kv_w,
    const float* __restrict__ p_w, const float* __restrict__ f1w,
    const float* __restrict__ f2w, const float* __restrict__ rel,
    u16* __restrict__ qp, u16* __restrict__ kvp, u16* __restrict__ pp,
    u16* __restrict__ f1p, u16* __restrict__ f2p, float* __restrict__ biasF)
{
    int t = blockIdx.x * 256 + threadIdx.x;
    if (t < 65536) {                                   // qp: 256x256
        int u = t;
        int e = u & 7, l = (u >> 3) & 63, ks = (u >> 9) & 7, ng = u >> 12;
        int k = ks * 32 + (l >> 4) * 8 + e;
        int n = ng * 16 + (l & 15);
        qp[u] = f2bf(q_w[k * 256 + n]);
    } else if (t < 196608) {                           // kvp: 256x512
        int u = t - 65536;
        int e = u & 7, l = (u >> 3) & 63, ks = (u >> 9) & 7, ng = u >> 12;
        int k = ks * 32 + (l >> 4) * 8 + e;
        int n = ng * 16 + (l & 15);
        kvp[u] = f2bf(kv_w[k * 512 + n]);
    } else if (t < 262144) {                           // pp: 256x256
        int u = t - 196608;
        int e = u & 7, l = (u >> 3) & 63, ks = (u >> 9) & 7, ng = u >> 12;
        int k = ks * 32 + (l >> 4) * 8 + e;
        int n = ng * 16 + (l & 15);
        pp[u] = f2bf(p_w[k * 256 + n]);
    } else if (t < 524288) {                           // f1p: 256x1024
        int u = t - 262144;
        int e = u & 7, l = (u >> 3) & 63, ks = (u >> 9) & 7, ng = u >> 12;
        int k = ks * 32 + (l >> 4) * 8 + e;
        int n = ng * 16 + (l & 15);
        f1p[u] = f2bf(f1w[k * 1024 + n]);
    } else if (t < 786432) {                           // f2p: 1024x256
        int u = t - 524288;
        int e = u & 7, l = (u >> 3) & 63, ks = (u >> 9) & 31, ng = u >> 14;
        int k = ks * 32 + (l >> 4) * 8 + e;
        int n = ng * 16 + (l & 15);
        f2p[u] = f2bf(f2w[k * 256 + n]);
    } else if (t < 819200) {                           // biasF 8*16*64*4 (*log2e)
        int u = t - 786432;
        int r = u & 3, l = (u >> 2) & 63, fr = (u >> 8) & 15, h = u >> 12;
        int fi = fr >> 2, fj = fr & 3;
        int m = fi * 16 + (l & 15);
        int n = fj * 16 + 4 * (l >> 4) + r;
        int idx = ((m >> 3) - (n >> 3) + 7) * 15 + ((m & 7) - (n & 7) + 7);
        biasF[u] = rel[idx * 8 + h] * 1.4426950408889634f;
    }
}

// Fast LN of one 256-col f32 row per 16-lane group (internal temps o0_/o1_).
#define LN_ROW16(SRCP, GG, BB, OUT0, OUT1)                                    \
    {                                                                         \
        float4 v0 = *(const float4*)(SRCP);                                   \
        float4 v1 = *(const float4*)(SRCP + 4);                               \
        float4 v2 = *(const float4*)(SRCP + 8);                               \
        float4 v3 = *(const float4*)(SRCP + 12);                              \
        float s = (v0.x + v0.y + v0.z + v0.w) + (v1.x + v1.y + v1.z + v1.w)   \
                + (v2.x + v2.y + v2.z + v2.w) + (v3.x + v3.y + v3.z + v3.w);  \
        float q = v0.x*v0.x + v0.y*v0.y + v0.z*v0.z + v0.w*v0.w               \
                + v1.x*v1.x + v1.y*v1.y + v1.z*v1.z + v1.w*v1.w               \
                + v2.x*v2.x + v2.y*v2.y + v2.z*v2.z + v2.w*v2.w               \
                + v3.x*v3.x + v3.y*v3.y + v3.z*v3.z + v3.w*v3.w;              \
        _Pragma("unroll")                                                     \
        for (int m_ = 1; m_ <= 8; m_ <<= 1) {                                 \
            s += __shfl_xor(s, m_, 64);                                       \
            q += __shfl_xor(q, m_, 64);                                       \
        }                                                                     \
        float mean = s * (1.0f / 256.0f);                                     \
        float rstd = rsqrtf(q * (1.0f / 256.0f) - mean * mean + 1e-5f);       \
        uint4 o0_, o1_;                                                       \
        o0_.x = pk2((v0.x-mean)*rstd*GG[0].x+BB[0].x, (v0.y-mean)*rstd*GG[0].y+BB[0].y); \
        o0_.y = pk2((v0.z-mean)*rstd*GG[0].z+BB[0].z, (v0.w-mean)*rstd*GG[0].w+BB[0].w); \
        o0_.z = pk2((v1.x-mean)*rstd*GG[1].x+BB[1].x, (v1.y-mean)*rstd*GG[1].y+BB[1].y); \
        o0_.w = pk2((v1.z-mean)*rstd*GG[1].z+BB[1].z, (v1.w-mean)*rstd*GG[1].w+BB[1].w); \
        o1_.x = pk2((v2.x-mean)*rstd*GG[2].x+BB[2].x, (v2.y-mean)*rstd*GG[2].y+BB[2].y); \
        o1_.y = pk2((v2.z-mean)*rstd*GG[2].z+BB[2].z, (v2.w-mean)*rstd*GG[2].w+BB[2].w); \
        o1_.z = pk2((v3.x-mean)*rstd*GG[3].x+BB[3].x, (v3.y-mean)*rstd*GG[3].y+BB[3].y); \
        o1_.w = pk2((v3.z-mean)*rstd*GG[3].z+BB[3].z, (v3.w-mean)*rstd*GG[3].w+BB[3].w); \
        OUT0 = o0_; OUT1 = o1_;                                               \
    }

// ----------------------------------------------------------- block mega -----
// ONE block = ONE window = the ENTIRE layer for its 64 rows. Phases as R19.
// NEW: (a) residual x1 prefetched to regs at kernel start (removes the
// mid-kernel L2-miss stall at proj time); (b) f32 output staged through a
// bank-optimal Fb LDS (stride 260) and written as full 1KB rows -> full
// cache lines (R19 showed 2.7x write amplification from fragment stores).
__global__ __launch_bounds__(512, 4) void block_mega(
    const float* __restrict__ x1, const float* __restrict__ x2,
    const float* __restrict__ n1g, const float* __restrict__ n1b,
    const bf16x8* __restrict__ qp, const bf16x8* __restrict__ kvp,
    const float* __restrict__ q_b, const float* __restrict__ kv_b,
    const float* __restrict__ biasF, const bf16x8* __restrict__ pp,
    const float* __restrict__ p_b,
    const float* __restrict__ n3g, const float* __restrict__ n3b,
    const bf16x8* __restrict__ f1p, const bf16x8* __restrict__ f2p,
    const float* __restrict__ f1b, const float* __restrict__ f2b,
    float* __restrict__ out)
{
    __shared__ __align__(16) char SMEM[74752];
    u16* Xl0  = (u16*)SMEM;            // phase 1-2
    u16* Xl1  = (u16*)(SMEM + 33792);  // phase 1-2
    u16* VtA  = (u16*)SMEM;            // phase 3 (after bar2)
    u16* Olds = (u16*)(SMEM + 40960);  // phase 3 (after bar2)
    u16* Xl4  = (u16*)SMEM;            // phase 4 (after bar3; over VtA)
    u16* Hl4  = (u16*)(SMEM + 40960);  // phase 4 (after bar4; over Olds)
    const int t = threadIdx.x, lane = t & 63, w = t >> 6;   // w = head
    const int g = lane >> 4, c = lane & 15;
    const int win = blockIdx.x;
    const int b_ = win >> 6, wh = (win >> 3) & 7, ww = win & 7;

    // ---- phase 0: prefetch proj-epilogue residual into registers ----
    float4 rr[4][2];
    #pragma unroll
    for (int i = 0; i < 4; i++) {
        int n = i * 16 + c;
        size_t nrow = (size_t)b_ * 4096 + (wh * 8 + (n >> 3)) * 64 + ww * 8 + (n & 7);
        #pragma unroll
        for (int j = 0; j < 2; j++)
            rr[i][j] = *(const float4*)(x1 + nrow * 256 + w * 32 + j * 16 + 4 * g);
    }

    // ---- phase 1: LN1 of both streams; 4 rows/iter (16-lane groups) ----
    {
        const int ln_sub = lane >> 4, ln_c = lane & 15;
        float4 GG[4], BB[4];
        #pragma unroll
        for (int j = 0; j < 4; j++) {
            GG[j] = *(const float4*)(n1g + ln_c * 16 + j * 4);
            BB[j] = *(const float4*)(n1b + ln_c * 16 + j * 4);
        }
        #pragma unroll
        for (int it = 0; it < 4; it++) {
            int idx = w * 16 + it * 4 + ln_sub;    // 0..127
            int st = idx >> 6, n = idx & 63;
            const float* src = st ? x2 : x1;
            size_t srow = (size_t)b_ * 4096 + (wh * 8 + (n >> 3)) * 64 + ww * 8 + (n & 7);
            const float* p = src + srow * 256 + ln_c * 16;
            uint4 o0, o1;
            LN_ROW16(p, GG, BB, o0, o1)
            u16* dst = st ? Xl1 : Xl0;
            char* base = (char*)dst + n * XROW + ln_c * 32;
            *(uint4*)(base) = o0;
            *(uint4*)(base + 16) = o1;
        }
    }
    __syncthreads();   // bar1: Xl ready

    // ---- phase 2: own-head Q/K/V GEMMs (K=256) ----
    const int srcA = c + 16 * ((2 * g) & 3);
    const int srcB = srcA + 16;
    const bool nhi = (g >= 2);

#define GEMM256(acc, WPTR, NGBASE, XSRC)                                      \
    { _Pragma("unroll")                                                       \
      for (int i = 0; i < 4; i++) { acc[i][0] = (f32x4){0,0,0,0};             \
                                    acc[i][1] = (f32x4){0,0,0,0}; }           \
      _Pragma("unroll")                                                       \
      for (int ks = 0; ks < 8; ks++) {                                        \
          bf16x8 wf[2], af[4];                                                \
          _Pragma("unroll")                                                   \
          for (int n = 0; n < 2; n++)                                         \
              wf[n] = WPTR[(size_t)(((NGBASE) + n) * 8 + ks) * 64 + lane];    \
          _Pragma("unroll")                                                   \
          for (int i = 0; i < 4; i++)                                         \
              af[i] = *(const bf16x8*)((char*)XSRC + (i * 16 + c) * XROW      \
                                       + g * 16 + ks * 64);                   \
          __builtin_amdgcn_s_setprio(1);                                      \
          _Pragma("unroll")                                                   \
          for (int i = 0; i < 4; i++)                                         \
              _Pragma("unroll")                                               \
              for (int n = 0; n < 2; n++)                                     \
                  acc[i][n] = __builtin_amdgcn_mfma_f32_16x16x32_bf16(        \
                      wf[n], af[i], acc[i][n], 0, 0, 0);                      \
          __builtin_amdgcn_s_setprio(0);                                      \
      } }

#define ADDBIAS(acc, BPTR, CBASE)                                             \
    { _Pragma("unroll")                                                       \
      for (int i = 0; i < 4; i++)                                             \
          _Pragma("unroll")                                                   \
          for (int n = 0; n < 2; n++) {                                       \
              float4 b4 = *(const float4*)((BPTR) + (CBASE) + n * 16 + 4 * g);\
              acc[i][n][0] += b4.x; acc[i][n][1] += b4.y;                     \
              acc[i][n][2] += b4.z; acc[i][n][3] += b4.w;                     \
          } }

#define REPACK(acc, frag)                                                     \
    { unsigned w0_[4][2], w1_[4][2];                                          \
      _Pragma("unroll")                                                       \
      for (int i = 0; i < 4; i++)                                             \
          _Pragma("unroll")                                                   \
          for (int n = 0; n < 2; n++) {                                       \
              w0_[i][n] = pk2(acc[i][n][0], acc[i][n][1]);                    \
              w1_[i][n] = pk2(acc[i][n][2], acc[i][n][3]);                    \
          }                                                                   \
      _Pragma("unroll")                                                       \
      for (int i = 0; i < 4; i++) {                                           \
          unsigned x0a = __shfl(w0_[i][0], srcA), x0b = __shfl(w0_[i][1], srcA);\
          unsigned y0a = __shfl(w1_[i][0], srcA), y0b = __shfl(w1_[i][1], srcA);\
          unsigned x1a = __shfl(w0_[i][0], srcB), x1b = __shfl(w0_[i][1], srcB);\
          unsigned y1a = __shfl(w1_[i][0], srcB), y1b = __shfl(w1_[i][1], srcB);\
          union { uint4 u; bf16x8 v; } cv;                                    \
          cv.u.x = nhi ? x0b : x0a;                                           \
          cv.u.y = nhi ? y0b : y0a;                                           \
          cv.u.z = nhi ? x1b : x1a;                                           \
          cv.u.w = nhi ? y1b : y1a;                                           \
          frag[i] = cv.v;                                                     \
      } }

    bf16x8 qf[4], kf[4];
    f32x4 av[4][2];
    {
        f32x4 acc[4][2];
        GEMM256(acc, kvp, 2 * w, Xl1)            // K
        ADDBIAS(acc, kv_b, w * 32)
        REPACK(acc, kf)
        GEMM256(acc, qp, 2 * w, Xl0)             // Q
        ADDBIAS(acc, q_b, w * 32)
        REPACK(acc, qf)
        GEMM256(av, kvp, 16 + 2 * w, Xl1)        // V
        ADDBIAS(av, kv_b, 256 + w * 32)
    }
    __syncthreads();   // bar2: Xl reads done -> safe to write VtA/Olds

    // V scatter: Vt[d][key], padded 80
    u16* vt = VtA + w * 32 * 80;
    #pragma unroll
    for (int i = 0; i < 4; i++)
        #pragma unroll
        for (int n = 0; n < 2; n++)
            #pragma unroll
            for (int r = 0; r < 4; r++)
                vt[(n * 16 + 4 * g + r) * 80 + i * 16 + c] = f2bf(av[i][n][r]);

    // QK^T; swapped mfma(K, Q)
    f32x4 s[4][4];
    #pragma unroll
    for (int i = 0; i < 4; i++)
        #pragma unroll
        for (int j = 0; j < 4; j++) {
            s[i][j] = (f32x4){0.f, 0.f, 0.f, 0.f};
            s[i][j] = __builtin_amdgcn_mfma_f32_16x16x32_bf16(kf[j], qf[i], s[i][j], 0, 0, 0);
        }

    // scale*log2e + pre-scaled rel-pos bias (log2-domain logits)
    #pragma unroll
    for (int i = 0; i < 4; i++)
        #pragma unroll
        for (int j = 0; j < 4; j++) {
            f32x4 bf4 = *(const f32x4*)(biasF + ((size_t)(w * 16 + i * 4 + j) * 64 + lane) * 4);
            #pragma unroll
            for (int r = 0; r < 4; r++) s[i][j][r] = s[i][j][r] * SCALE2 + bf4[r];
        }

    // softmax over keys (exp2)
    #pragma unroll
    for (int i = 0; i < 4; i++) {
        float mx = -1e30f;
        #pragma unroll
        for (int j = 0; j < 4; j++)
            #pragma unroll
            for (int r = 0; r < 4; r++) mx = fmaxf(mx, s[i][j][r]);
        mx = fmaxf(mx, __shfl_xor(mx, 16, 64));
        mx = fmaxf(mx, __shfl_xor(mx, 32, 64));
        float sum = 0.f;
        #pragma unroll
        for (int j = 0; j < 4; j++)
            #pragma unroll
            for (int r = 0; r < 4; r++) {
                float e = exp2f(s[i][j][r] - mx);
                s[i][j][r] = e; sum += e;
            }
        sum += __shfl_xor(sum, 16, 64);
        sum += __shfl_xor(sum, 32, 64);
        float inv = 1.f / sum;
        #pragma unroll
        for (int j = 0; j < 4; j++)
            #pragma unroll
            for (int r = 0; r < 4; r++) s[i][j][r] *= inv;
    }

    // P repack + PV
    unsigned pw0[4][4], pw1[4][4];
    #pragma unroll
    for (int i = 0; i < 4; i++)
        #pragma unroll
        for (int j = 0; j < 4; j++) {
            pw0[i][j] = pk2(s[i][j][0], s[i][j][1]);
            pw1[i][j] = pk2(s[i][j][2], s[i][j][3]);
        }
    f32x4 o[4][2];
    #pragma unroll
    for (int i = 0; i < 4; i++) { o[i][0] = (f32x4){0,0,0,0}; o[i][1] = (f32x4){0,0,0,0}; }
    #pragma unroll
    for (int ks = 0; ks < 2; ks++) {
        bf16x8 pa[4], vb[2];
        #pragma unroll
        for (int i = 0; i < 4; i++) {
            unsigned a0 = __shfl(pw0[i][2 * ks], srcA), b0 = __shfl(pw0[i][2 * ks + 1], srcA);
            unsigned a1 = __shfl(pw1[i][2 * ks], srcA), b1 = __shfl(pw1[i][2 * ks + 1], srcA);
            unsigned a2 = __shfl(pw0[i][2 * ks], srcB), b2 = __shfl(pw0[i][2 * ks + 1], srcB);
            unsigned a3 = __shfl(pw1[i][2 * ks], srcB), b3 = __shfl(pw1[i][2 * ks + 1], srcB);
            union { uint4 u; bf16x8 v; } cv;
            cv.u.x = nhi ? b0 : a0;
            cv.u.y = nhi ? b1 : a1;
            cv.u.z = nhi ? b2 : a2;
            cv.u.w = nhi ? b3 : a3;
            pa[i] = cv.v;
        }
        #pragma unroll
        for (int j = 0; j < 2; j++) {
            int d = j * 16 + c;
            vb[j] = *(const bf16x8*)(vt + d * 80 + ks * 32 + 8 * g);
        }
        #pragma unroll
        for (int i = 0; i < 4; i++)
            #pragma unroll
            for (int j = 0; j < 2; j++)
                o[i][j] = __builtin_amdgcn_mfma_f32_16x16x32_bf16(vb[j], pa[i], o[i][j], 0, 0, 0);
    }

    // O -> Olds
    #pragma unroll
    for (int i = 0; i < 4; i++) {
        int row = i * 16 + c;
        #pragma unroll
        for (int j = 0; j < 2; j++) {
            uint2 pk = { pk2(o[i][j][0], o[i][j][1]), pk2(o[i][j][2], o[i][j][3]) };
            *(uint2*)((char*)Olds + row * XROW + w * 64 + j * 32 + g * 8) = pk;
        }
    }
    __syncthreads();   // bar3: all heads' O in Olds; all Vt reads done

    // proj: wave w -> out cols w*32..+32, K=256 from Olds
    f32x4 ap[4][2];
    #pragma unroll
    for (int i = 0; i < 4; i++) { ap[i][0] = (f32x4){0,0,0,0}; ap[i][1] = (f32x4){0,0,0,0}; }
    #pragma unroll
    for (int ks = 0; ks < 8; ks++) {
        bf16x8 wf[2], ah[4];
        #pragma unroll
        for (int n = 0; n < 2; n++)
            wf[n] = pp[(size_t)((w * 2 + n) * 8 + ks) * 64 + lane];
        #pragma unroll
        for (int i = 0; i < 4; i++)
            ah[i] = *(const bf16x8*)((char*)Olds + (i * 16 + c) * XROW
                                     + g * 16 + ks * 64);
        __builtin_amdgcn_s_setprio(1);
        #pragma unroll
        for (int i = 0; i < 4; i++)
            #pragma unroll
            for (int n = 0; n < 2; n++)
                ap[i][n] = __builtin_amdgcn_mfma_f32_16x16x32_bf16(
                    wf[n], ah[i], ap[i][n], 0, 0, 0);
        __builtin_amdgcn_s_setprio(0);
    }

    // x = proj + p_b + prefetched residual -> bf16 packed regs + Xl4
    uint2 xs[4][2];
    #pragma unroll
    for (int i = 0; i < 4; i++) {
        #pragma unroll
        for (int j = 0; j < 2; j++) {
            int col = w * 32 + j * 16 + 4 * g;
            float4 b4 = *(const float4*)(p_b + col);
            float4 r4 = rr[i][j];
            uint2 pk = { pk2(ap[i][j][0] + b4.x + r4.x, ap[i][j][1] + b4.y + r4.y),
                         pk2(ap[i][j][2] + b4.z + r4.z, ap[i][j][3] + b4.w + r4.w) };
            xs[i][j] = pk;
            *(uint2*)((char*)Xl4 + (i * 16 + c) * XROW + w * 64 + j * 32 + g * 8) = pk;
        }
    }
    __syncthreads();   // bar4: full x in Xl4; all Olds reads done

    // ---- phase 4a: LN3 in place on Xl4 (16-lane groups, 2 iters) ----
    {
        const int ln_sub = lane >> 4, ln_c = lane & 15;
        float4 G3[4], B3[4];
        #pragma unroll
        for (int j = 0; j < 4; j++) {
            G3[j] = *(const float4*)(n3g + ln_c * 16 + j * 4);
            B3[j] = *(const float4*)(n3b + ln_c * 16 + j * 4);
        }
        const float* G = (const float*)G3;
        const float* B = (const float*)B3;
        #pragma unroll
        for (int it = 0; it < 2; it++) {
            int row = w * 8 + it * 4 + ln_sub;
            char* base = (char*)Xl4 + row * XROW + ln_c * 32;
            uint4 rv = *(const uint4*)(base);
            uint4 rw = *(const uint4*)(base + 16);
            float v[16];
            v[0] = bf2f((u16)rv.x);  v[1] = bf2f((u16)(rv.x >> 16));
            v[2] = bf2f((u16)rv.y);  v[3] = bf2f((u16)(rv.y >> 16));
            v[4] = bf2f((u16)rv.z);  v[5] = bf2f((u16)(rv.z >> 16));
            v[6] = bf2f((u16)rv.w);  v[7] = bf2f((u16)(rv.w >> 16));
            v[8] = bf2f((u16)rw.x);  v[9] = bf2f((u16)(rw.x >> 16));
            v[10] = bf2f((u16)rw.y); v[11] = bf2f((u16)(rw.y >> 16));
            v[12] = bf2f((u16)rw.z); v[13] = bf2f((u16)(rw.z >> 16));
            v[14] = bf2f((u16)rw.w); v[15] = bf2f((u16)(rw.w >> 16));
            float sm = 0.f, qm = 0.f;
            #pragma unroll
            for (int e = 0; e < 16; e++) { sm += v[e]; qm += v[e] * v[e]; }
            #pragma unroll
            for (int m_ = 1; m_ <= 8; m_ <<= 1) {
                sm += __shfl_xor(sm, m_, 64);
                qm += __shfl_xor(qm, m_, 64);
            }
            float mean = sm * (1.0f / 256.0f);
            float rstd = rsqrtf(qm * (1.0f / 256.0f) - mean * mean + 1e-5f);
            uint4 o0, o1;
            o0.x = pk2((v[0]-mean)*rstd*G[0]+B[0],  (v[1]-mean)*rstd*G[1]+B[1]);
            o0.y = pk2((v[2]-mean)*rstd*G[2]+B[2],  (v[3]-mean)*rstd*G[3]+B[3]);
            o0.z = pk2((v[4]-mean)*rstd*G[4]+B[4],  (v[5]-mean)*rstd*G[5]+B[5]);
            o0.w = pk2((v[6]-mean)*rstd*G[6]+B[6],  (v[7]-mean)*rstd*G[7]+B[7]);
            o1.x = pk2((v[8]-mean)*rstd*G[8]+B[8],  (v[9]-mean)*rstd*G[9]+B[9]);
            o1.y = pk2((v[10]-mean)*rstd*G[10]+B[10],(v[11]-mean)*rstd*G[11]+B[11]);
            o1.z = pk2((v[12]-mean)*rstd*G[12]+B[12],(v[13]-mean)*rstd*G[13]+B[13]);
            o1.w = pk2((v[14]-mean)*rstd*G[14]+B[14],(v[15]-mean)*rstd*G[15]+B[15]);
            *(uint4*)(base) = o0;
            *(uint4*)(base + 16) = o1;
        }
    }
    __syncthreads();   // bar5: LN3(x) in Xl4

    // ---- phase 4b: MLP (fc1+gelu -> Hl4; fc2 accumulate) ----
    f32x4 acc2[4][2];
    #pragma unroll
    for (int i = 0; i < 4; i++) { acc2[i][0] = (f32x4){0,0,0,0}; acc2[i][1] = (f32x4){0,0,0,0}; }

    #pragma unroll
    for (int hc = 0; hc < 4; hc++) {
        f32x4 acc1[4][2];
        #pragma unroll
        for (int i = 0; i < 4; i++) { acc1[i][0] = (f32x4){0,0,0,0}; acc1[i][1] = (f32x4){0,0,0,0}; }

        const bf16x8* f1base = f1p + (size_t)((hc * 16 + w * 2) * 8) * 64 + lane;
        bf16x8 wA[2], wB[2];
        #pragma unroll
        for (int n = 0; n < 2; n++) wA[n] = f1base[(n * 8 + 0) * 64];

#define FC1_STEP(WREG, ks_)                                                   \
        {                                                                     \
            bf16x8 af[4];                                                     \
            _Pragma("unroll")                                                 \
            for (int i = 0; i < 4; i++)                                       \
                af[i] = *(const bf16x8*)((char*)Xl4 + (i * 16 + c) * XROW     \
                                         + g * 16 + (ks_) * 64);             \
            __builtin_amdgcn_s_setprio(1);                                    \
            _Pragma("unroll")                                                 \
            for (int i = 0; i < 4; i++)                                       \
                _Pragma("unroll")                                             \
                for (int n = 0; n < 2; n++)                                   \
                    acc1[i][n] = __builtin_amdgcn_mfma_f32_16x16x32_bf16(     \
                        WREG[n], af[i], acc1[i][n], 0, 0, 0);                 \
            __builtin_amdgcn_s_setprio(0);                                    \
        }

        #pragma unroll
        for (int ks = 0; ks < 8; ks += 2) {
            #pragma unroll
            for (int n = 0; n < 2; n++) wB[n] = f1base[(n * 8 + ks + 1) * 64];
            FC1_STEP(wA, ks)
            if (ks + 2 < 8) {
                #pragma unroll
                for (int n = 0; n < 2; n++) wA[n] = f1base[(n * 8 + ks + 2) * 64];
            }
            FC1_STEP(wB, ks + 1)
        }
#undef FC1_STEP

        #pragma unroll
        for (int i = 0; i < 4; i++) {
            int row = i * 16 + c;
            #pragma unroll
            for (int n = 0; n < 2; n++) {
                float4 b4 = *(const float4*)(f1b + hc * 256 + w * 32 + n * 16 + 4 * g);
                float h0 = gelu_s(acc1[i][n][0] + b4.x);
                float h1 = gelu_s(acc1[i][n][1] + b4.y);
                float h2 = gelu_s(acc1[i][n][2] + b4.z);
                float h3 = gelu_s(acc1[i][n][3] + b4.w);
                uint2 pk = { pk2(h0, h1), pk2(h2, h3) };
                *(uint2*)((char*)Hl4 + row * XROW + w * 64 + n * 32 + g * 8) = pk;
            }
        }
        __syncthreads();

        const bf16x8* f2base = f2p + (size_t)((w * 2) * 32 + hc * 8) * 64 + lane;
        #pragma unroll
        for (int n = 0; n < 2; n++) wA[n] = f2base[(n * 32 + 0) * 64];

#define FC2_STEP(WREG, ks_)                                                   \
        {                                                                     \
            bf16x8 ah[4];                                                     \
            _Pragma("unroll")                                                 \
            for (int i = 0; i < 4; i++)                                       \
                ah[i] = *(const bf16x8*)((char*)Hl4 + (i * 16 + c) * XROW     \
                                         + g * 16 + (ks_) * 64);             \
            __builtin_amdgcn_s_setprio(1);                                    \
            _Pragma("unroll")                                                 \
            for (int i = 0; i < 4; i++)                                       \
                _Pragma("unroll")                                             \
                for (int n = 0; n < 2; n++)                                   \
                    acc2[i][n] = __builtin_amdgcn_mfma_f32_16x16x32_bf16(     \
                        WREG[n], ah[i], acc2[i][n], 0, 0, 0);                 \
            __builtin_amdgcn_s_setprio(0);                                    \
        }

        #pragma unroll
        for (int ks = 0; ks < 8; ks += 2) {
            #pragma unroll
            for (int n = 0; n < 2; n++) wB[n] = f2base[(n * 32 + ks + 1) * 64];
            FC2_STEP(wA, ks)
            if (ks + 2 < 8) {
                #pragma unroll
                for (int n = 0; n < 2; n++) wA[n] = f2base[(n * 32 + ks + 2) * 64];
            }
            FC2_STEP(wB, ks + 1)
        }
#undef FC2_STEP
        __syncthreads();
    }

    // ---- epilogue: stage f32 rows in Fb (stride 260), then write full
    //      1KB rows -> full cache lines (kills write amplification) ----
    {
        float* Fb = (float*)SMEM;    // entire arena dead after last barrier
        #pragma unroll
        for (int i = 0; i < 4; i++) {
            int row = i * 16 + c;
            #pragma unroll
            for (int j = 0; j < 2; j++) {
                int coloff = w * 32 + j * 16 + 4 * g;
                float4 b4 = *(const float4*)(f2b + coloff);
                uint2 rr2 = xs[i][j];
                f32x4 ov = { acc2[i][j][0] + b4.x + bf2f((u16)rr2.x),
                             acc2[i][j][1] + b4.y + bf2f((u16)(rr2.x >> 16)),
                             acc2[i][j][2] + b4.z + bf2f((u16)rr2.y),
                             acc2[i][j][3] + b4.w + bf2f((u16)(rr2.y >> 16)) };
                *(f32x4*)(Fb + row * FROW + coloff) = ov;
            }
        }
        __syncthreads();
        const int ln_sub = lane >> 4, ln_c = lane & 15;
        #pragma unroll
        for (int it = 0; it < 2; it++) {
            int n = w * 8 + it * 4 + ln_sub;
            size_t nrow = (size_t)b_ * 4096 + (wh * 8 + (n >> 3)) * 64 + ww * 8 + (n & 7);
            const float* sp = Fb + n * FROW + ln_c * 16;
            float4 a0 = *(const float4*)(sp);
            float4 a1 = *(const float4*)(sp + 4);
            float4 a2 = *(const float4*)(sp + 8);
            float4 a3 = *(const float4*)(sp + 12);
            float* dst = out + nrow * 256 + ln_c * 16;
            *(float4*)(dst) = a0;
            *(float4*)(dst + 4) = a1;
            *(float4*)(dst + 8) = a2;
            *(float4*)(dst + 12) = a3;
        }
    }
#undef GEMM256
#undef ADDBIAS
#undef REPACK
}

// -------------------------------------------------------------- launch ------
// Workspace (peak ~2.1 MB): weights only.
extern "C" void kernel_launch(void* const* d_in, const int* in_sizes, int n_in,
                              void* d_out, int out_size, void* d_ws, size_t ws_size,
                              hipStream_t stream)
{
    const float* x1  = (const float*)d_in[0];
    const float* x2  = (const float*)d_in[1];
    const float* n1g = (const float*)d_in[2];
    const float* n1b = (const float*)d_in[3];
    const float* q_w = (const float*)d_in[4];
    const float* q_b = (const float*)d_in[5];
    const float* kv_w= (const float*)d_in[6];
    const float* kv_b= (const float*)d_in[7];
    const float* p_w = (const float*)d_in[8];
    const float* p_b = (const float*)d_in[9];
    const float* rel = (const float*)d_in[10];
    const float* n3g = (const float*)d_in[11];
    const float* n3b = (const float*)d_in[12];
    const float* f1w = (const float*)d_in[13];
    const float* f1b = (const float*)d_in[14];
    const float* f2w = (const float*)d_in[15];
    const float* f2b = (const float*)d_in[16];

    char* ws = (char*)d_ws;
    u16*   qp    = (u16*)(ws + 0);
    u16*   kvp   = (u16*)(ws + 131072);
    u16*   pp    = (u16*)(ws + 393216);
    u16*   f1p   = (u16*)(ws + 524288);
    u16*   f2p   = (u16*)(ws + 1048576);
    float* biasF = (float*)(ws + 1572864);

    float* out = (float*)d_out;

    prep_k<<<3200, 256, 0, stream>>>(q_w, kv_w, p_w, f1w, f2w, rel,
                                     qp, kvp, pp, f1p, f2p, biasF);
    block_mega<<<1024, 512, 0, stream>>>(x1, x2, n1g, n1b, (const bf16x8*)qp,
                                         (const bf16x8*)kvp, q_b, kv_b, biasF,
                                         (const bf16x8*)pp, p_b, n3g, n3b,
                                         (const bf16x8*)f1p, (const bf16x8*)f2p,
                                         f1b, f2b, out);
}

// Round 21
// 195.658 us; speedup vs baseline: 1.1279x; 1.1279x over previous
//
#include <hip/hip_runtime.h>

typedef __bf16 bf16x8 __attribute__((ext_vector_type(8)));
typedef float f32x4 __attribute__((ext_vector_type(4)));
using u16 = unsigned short;

#define SCALE2 (0.17677669529663689f * 1.4426950408889634f)  // 32^-0.5 * log2(e)
#define XROW 528                    // padded LDS row stride (264 u16)
#define FROW 260                    // padded f32 LDS row stride (floats)

// Native bf16 casts (RTNE) -> compiler fuses pairs into v_cvt_pk_bf16_f32.
__device__ __forceinline__ u16 f2bf(float f) {
    union { __bf16 h; u16 u; } x; x.h = (__bf16)f; return x.u;
}
__device__ __forceinline__ unsigned pk2(float a, float b) {
    union { struct { __bf16 lo, hi; } s; unsigned u; } x;
    x.s.lo = (__bf16)a; x.s.hi = (__bf16)b; return x.u;
}
__device__ __forceinline__ float bf2f(u16 h) {
    union { unsigned u; float f; } x; x.u = ((unsigned)h) << 16; return x.f;
}
// gelu = x * sigmoid(1.5957691*(x+0.044715x^3)); exp folded to native exp2
__device__ __forceinline__ float gelu_s(float x) {
    float u = 2.3022150048054216f * x * (1.f + 0.044715f * x * x); // *log2(e)
    float e = exp2f(-u);
    return x / (1.f + e);
}

// ---------------------------------------------------------------- prep ------
__global__ __launch_bounds__(256) void prep_k(
    const float* __restrict__ q_w, const float* __restrict__ kv_w,
    const float* __restrict__ p_w, const float* __restrict__ f1w,
    const float* __restrict__ f2w, const float* __restrict__ rel,
    u16* __restrict__ qp, u16* __restrict__ kvp, u16* __restrict__ pp,
    u16* __restrict__ f1p, u16* __restrict__ f2p, float* __restrict__ biasF)
{
    int t = blockIdx.x * 256 + threadIdx.x;
    if (t < 65536) {                                   // qp: 256x256
        int u = t;
        int e = u & 7, l = (u >> 3) & 63, ks = (u >> 9) & 7, ng = u >> 12;
        int k = ks * 32 + (l >> 4) * 8 + e;
        int n = ng * 16 + (l & 15);
        qp[u] = f2bf(q_w[k * 256 + n]);
    } else if (t < 196608) {                           // kvp: 256x512
        int u = t - 65536;
        int e = u & 7, l = (u >> 3) & 63, ks = (u >> 9) & 7, ng = u >> 12;
        int k = ks * 32 + (l >> 4) * 8 + e;
        int n = ng * 16 + (l & 15);
        kvp[u] = f2bf(kv_w[k * 512 + n]);
    } else if (t < 262144) {                           // pp: 256x256
        int u = t - 196608;
        int e = u & 7, l = (u >> 3) & 63, ks = (u >> 9) & 7, ng = u >> 12;
        int k = ks * 32 + (l >> 4) * 8 + e;
        int n = ng * 16 + (l & 15);
        pp[u] = f2bf(p_w[k * 256 + n]);
    } else if (t < 524288) {                           // f1p: 256x1024
        int u = t - 262144;
        int e = u & 7, l = (u >> 3) & 63, ks = (u >> 9) & 7, ng = u >> 12;
        int k = ks * 32 + (l >> 4) * 8 + e;
        int n = ng * 16 + (l & 15);
        f1p[u] = f2bf(f1w[k * 1024 + n]);
    } else if (t < 786432) {                           // f2p: 1024x256
        int u = t - 524288;
        int e = u & 7, l = (u >> 3) & 63, ks = (u >> 9) & 31, ng = u >> 14;
        int k = ks * 32 + (l >> 4) * 8 + e;
        int n = ng * 16 + (l & 15);
        f2p[u] = f2bf(f2w[k * 256 + n]);
    } else if (t < 819200) {                           // biasF 8*16*64*4 (*log2e)
        int u = t - 786432;
        int r = u & 3, l = (u >> 2) & 63, fr = (u >> 8) & 15, h = u >> 12;
        int fi = fr >> 2, fj = fr & 3;
        int m = fi * 16 + (l & 15);
        int n = fj * 16 + 4 * (l >> 4) + r;
        int idx = ((m >> 3) - (n >> 3) + 7) * 15 + ((m & 7) - (n & 7) + 7);
        biasF[u] = rel[idx * 8 + h] * 1.4426950408889634f;
    }
}

// Fast LN of one 256-col f32 row per 16-lane group (internal temps o0_/o1_).
#define LN_ROW16(SRCP, GG, BB, OUT0, OUT1)                                    \
    {                                                                         \
        float4 v0 = *(const float4*)(SRCP);                                   \
        float4 v1 = *(const float4*)(SRCP + 4);                               \
        float4 v2 = *(const float4*)(SRCP + 8);                               \
        float4 v3 = *(const float4*)(SRCP + 12);                              \
        float s = (v0.x + v0.y + v0.z + v0.w) + (v1.x + v1.y + v1.z + v1.w)   \
                + (v2.x + v2.y + v2.z + v2.w) + (v3.x + v3.y + v3.z + v3.w);  \
        float q = v0.x*v0.x + v0.y*v0.y + v0.z*v0.z + v0.w*v0.w               \
                + v1.x*v1.x + v1.y*v1.y + v1.z*v1.z + v1.w*v1.w               \
                + v2.x*v2.x + v2.y*v2.y + v2.z*v2.z + v2.w*v2.w               \
                + v3.x*v3.x + v3.y*v3.y + v3.z*v3.z + v3.w*v3.w;              \
        _Pragma("unroll")                                                     \
        for (int m_ = 1; m_ <= 8; m_ <<= 1) {                                 \
            s += __shfl_xor(s, m_, 64);                                       \
            q += __shfl_xor(q, m_, 64);                                       \
        }                                                                     \
        float mean = s * (1.0f / 256.0f);                                     \
        float rstd = rsqrtf(q * (1.0f / 256.0f) - mean * mean + 1e-5f);       \
        uint4 o0_, o1_;                                                       \
        o0_.x = pk2((v0.x-mean)*rstd*GG[0].x+BB[0].x, (v0.y-mean)*rstd*GG[0].y+BB[0].y); \
        o0_.y = pk2((v0.z-mean)*rstd*GG[0].z+BB[0].z, (v0.w-mean)*rstd*GG[0].w+BB[0].w); \
        o0_.z = pk2((v1.x-mean)*rstd*GG[1].x+BB[1].x, (v1.y-mean)*rstd*GG[1].y+BB[1].y); \
        o0_.w = pk2((v1.z-mean)*rstd*GG[1].z+BB[1].z, (v1.w-mean)*rstd*GG[1].w+BB[1].w); \
        o1_.x = pk2((v2.x-mean)*rstd*GG[2].x+BB[2].x, (v2.y-mean)*rstd*GG[2].y+BB[2].y); \
        o1_.y = pk2((v2.z-mean)*rstd*GG[2].z+BB[2].z, (v2.w-mean)*rstd*GG[2].w+BB[2].w); \
        o1_.z = pk2((v3.x-mean)*rstd*GG[3].x+BB[3].x, (v3.y-mean)*rstd*GG[3].y+BB[3].y); \
        o1_.w = pk2((v3.z-mean)*rstd*GG[3].z+BB[3].z, (v3.w-mean)*rstd*GG[3].w+BB[3].w); \
        OUT0 = o0_; OUT1 = o1_;                                               \
    }

// ----------------------------------------------------------- block mega -----
// ONE block = ONE window = ENTIRE layer for its 64 rows (R19 base, 199 µs)
// + coalesced epilogue: f32 out staged in Fb, each WAVE writes one full
// 1KB row per store (8 full 128B lines, no partial-line flushes).
__global__ __launch_bounds__(512, 4) void block_mega(
    const float* __restrict__ x1, const float* __restrict__ x2,
    const float* __restrict__ n1g, const float* __restrict__ n1b,
    const bf16x8* __restrict__ qp, const bf16x8* __restrict__ kvp,
    const float* __restrict__ q_b, const float* __restrict__ kv_b,
    const float* __restrict__ biasF, const bf16x8* __restrict__ pp,
    const float* __restrict__ p_b,
    const float* __restrict__ n3g, const float* __restrict__ n3b,
    const bf16x8* __restrict__ f1p, const bf16x8* __restrict__ f2p,
    const float* __restrict__ f1b, const float* __restrict__ f2b,
    float* __restrict__ out)
{
    __shared__ __align__(16) char SMEM[74752];
    u16* Xl0  = (u16*)SMEM;            // phase 1-2
    u16* Xl1  = (u16*)(SMEM + 33792);  // phase 1-2
    u16* VtA  = (u16*)SMEM;            // phase 3 (after bar2)
    u16* Olds = (u16*)(SMEM + 40960);  // phase 3 (after bar2)
    u16* Xl4  = (u16*)SMEM;            // phase 4 (after bar3; over VtA)
    u16* Hl4  = (u16*)(SMEM + 40960);  // phase 4 (after bar4; over Olds)
    const int t = threadIdx.x, lane = t & 63, w = t >> 6;   // w = head
    const int g = lane >> 4, c = lane & 15;
    const int win = blockIdx.x;
    const int b_ = win >> 6, wh = (win >> 3) & 7, ww = win & 7;

    // ---- phase 1: LN1 of both streams; 4 rows/iter (16-lane groups) ----
    {
        const int ln_sub = lane >> 4, ln_c = lane & 15;
        float4 GG[4], BB[4];
        #pragma unroll
        for (int j = 0; j < 4; j++) {
            GG[j] = *(const float4*)(n1g + ln_c * 16 + j * 4);
            BB[j] = *(const float4*)(n1b + ln_c * 16 + j * 4);
        }
        #pragma unroll
        for (int it = 0; it < 4; it++) {
            int idx = w * 16 + it * 4 + ln_sub;    // 0..127
            int st = idx >> 6, n = idx & 63;
            const float* src = st ? x2 : x1;
            size_t srow = (size_t)b_ * 4096 + (wh * 8 + (n >> 3)) * 64 + ww * 8 + (n & 7);
            const float* p = src + srow * 256 + ln_c * 16;
            uint4 o0, o1;
            LN_ROW16(p, GG, BB, o0, o1)
            u16* dst = st ? Xl1 : Xl0;
            char* base = (char*)dst + n * XROW + ln_c * 32;
            *(uint4*)(base) = o0;
            *(uint4*)(base + 16) = o1;
        }
    }
    __syncthreads();   // bar1: Xl ready

    // ---- phase 2: own-head Q/K/V GEMMs (K=256), weight dbuf ----
    const int srcA = c + 16 * ((2 * g) & 3);
    const int srcB = srcA + 16;
    const bool nhi = (g >= 2);

#define GEMM256(acc, WPTR, NGBASE, XSRC)                                      \
    { _Pragma("unroll")                                                       \
      for (int i = 0; i < 4; i++) { acc[i][0] = (f32x4){0,0,0,0};             \
                                    acc[i][1] = (f32x4){0,0,0,0}; }           \
      bf16x8 wcur[2], wnxt[2];                                                \
      _Pragma("unroll")                                                       \
      for (int n = 0; n < 2; n++)                                             \
          wcur[n] = WPTR[(size_t)(((NGBASE) + n) * 8 + 0) * 64 + lane];       \
      _Pragma("unroll")                                                       \
      for (int ks = 0; ks < 8; ks++) {                                        \
          if (ks + 1 < 8) {                                                   \
              _Pragma("unroll")                                               \
              for (int n = 0; n < 2; n++)                                     \
                  wnxt[n] = WPTR[(size_t)(((NGBASE) + n) * 8 + ks + 1) * 64 + lane]; \
          }                                                                   \
          bf16x8 af[4];                                                       \
          _Pragma("unroll")                                                   \
          for (int i = 0; i < 4; i++)                                         \
              af[i] = *(const bf16x8*)((char*)XSRC + (i * 16 + c) * XROW      \
                                       + g * 16 + ks * 64);                   \
          __builtin_amdgcn_s_setprio(1);                                      \
          _Pragma("unroll")                                                   \
          for (int i = 0; i < 4; i++)                                         \
              _Pragma("unroll")                                               \
              for (int n = 0; n < 2; n++)                                     \
                  acc[i][n] = __builtin_amdgcn_mfma_f32_16x16x32_bf16(        \
                      wcur[n], af[i], acc[i][n], 0, 0, 0);                    \
          __builtin_amdgcn_s_setprio(0);                                      \
          _Pragma("unroll")                                                   \
          for (int n = 0; n < 2; n++) wcur[n] = wnxt[n];                      \
      } }

#define ADDBIAS(acc, BPTR, CBASE)                                             \
    { _Pragma("unroll")                                                       \
      for (int i = 0; i < 4; i++)                                             \
          _Pragma("unroll")                                                   \
          for (int n = 0; n < 2; n++) {                                       \
              float4 b4 = *(const float4*)((BPTR) + (CBASE) + n * 16 + 4 * g);\
              acc[i][n][0] += b4.x; acc[i][n][1] += b4.y;                     \
              acc[i][n][2] += b4.z; acc[i][n][3] += b4.w;                     \
          } }

#define REPACK(acc, frag)                                                     \
    { unsigned w0_[4][2], w1_[4][2];                                          \
      _Pragma("unroll")                                                       \
      for (int i = 0; i < 4; i++)                                             \
          _Pragma("unroll")                                                   \
          for (int n = 0; n < 2; n++) {                                       \
              w0_[i][n] = pk2(acc[i][n][0], acc[i][n][1]);                    \
              w1_[i][n] = pk2(acc[i][n][2], acc[i][n][3]);                    \
          }                                                                   \
      _Pragma("unroll")                                                       \
      for (int i = 0; i < 4; i++) {                                           \
          unsigned x0a = __shfl(w0_[i][0], srcA), x0b = __shfl(w0_[i][1], srcA);\
          unsigned y0a = __shfl(w1_[i][0], srcA), y0b = __shfl(w1_[i][1], srcA);\
          unsigned x1a = __shfl(w0_[i][0], srcB), x1b = __shfl(w0_[i][1], srcB);\
          unsigned y1a = __shfl(w1_[i][0], srcB), y1b = __shfl(w1_[i][1], srcB);\
          union { uint4 u; bf16x8 v; } cv;                                    \
          cv.u.x = nhi ? x0b : x0a;                                           \
          cv.u.y = nhi ? y0b : y0a;                                           \
          cv.u.z = nhi ? x1b : x1a;                                           \
          cv.u.w = nhi ? y1b : y1a;                                           \
          frag[i] = cv.v;                                                     \
      } }

    bf16x8 qf[4], kf[4];
    f32x4 av[4][2];
    {
        f32x4 acc[4][2];
        GEMM256(acc, kvp, 2 * w, Xl1)            // K
        ADDBIAS(acc, kv_b, w * 32)
        REPACK(acc, kf)
        GEMM256(acc, qp, 2 * w, Xl0)             // Q
        ADDBIAS(acc, q_b, w * 32)
        REPACK(acc, qf)
        GEMM256(av, kvp, 16 + 2 * w, Xl1)        // V
        ADDBIAS(av, kv_b, 256 + w * 32)
    }
    __syncthreads();   // bar2: Xl reads done -> safe to write VtA/Olds

    // V scatter: Vt[d][key], padded 80
    u16* vt = VtA + w * 32 * 80;
    #pragma unroll
    for (int i = 0; i < 4; i++)
        #pragma unroll
        for (int n = 0; n < 2; n++)
            #pragma unroll
            for (int r = 0; r < 4; r++)
                vt[(n * 16 + 4 * g + r) * 80 + i * 16 + c] = f2bf(av[i][n][r]);

    // QK^T; swapped mfma(K, Q)
    f32x4 s[4][4];
    #pragma unroll
    for (int i = 0; i < 4; i++)
        #pragma unroll
        for (int j = 0; j < 4; j++) {
            s[i][j] = (f32x4){0.f, 0.f, 0.f, 0.f};
            s[i][j] = __builtin_amdgcn_mfma_f32_16x16x32_bf16(kf[j], qf[i], s[i][j], 0, 0, 0);
        }

    // scale*log2e + pre-scaled rel-pos bias (log2-domain logits)
    #pragma unroll
    for (int i = 0; i < 4; i++)
        #pragma unroll
        for (int j = 0; j < 4; j++) {
            f32x4 bf4 = *(const f32x4*)(biasF + ((size_t)(w * 16 + i * 4 + j) * 64 + lane) * 4);
            #pragma unroll
            for (int r = 0; r < 4; r++) s[i][j][r] = s[i][j][r] * SCALE2 + bf4[r];
        }

    // softmax over keys (exp2)
    #pragma unroll
    for (int i = 0; i < 4; i++) {
        float mx = -1e30f;
        #pragma unroll
        for (int j = 0; j < 4; j++)
            #pragma unroll
            for (int r = 0; r < 4; r++) mx = fmaxf(mx, s[i][j][r]);
        mx = fmaxf(mx, __shfl_xor(mx, 16, 64));
        mx = fmaxf(mx, __shfl_xor(mx, 32, 64));
        float sum = 0.f;
        #pragma unroll
        for (int j = 0; j < 4; j++)
            #pragma unroll
            for (int r = 0; r < 4; r++) {
                float e = exp2f(s[i][j][r] - mx);
                s[i][j][r] = e; sum += e;
            }
        sum += __shfl_xor(sum, 16, 64);
        sum += __shfl_xor(sum, 32, 64);
        float inv = 1.f / sum;
        #pragma unroll
        for (int j = 0; j < 4; j++)
            #pragma unroll
            for (int r = 0; r < 4; r++) s[i][j][r] *= inv;
    }

    // P repack + PV
    unsigned pw0[4][4], pw1[4][4];
    #pragma unroll
    for (int i = 0; i < 4; i++)
        #pragma unroll
        for (int j = 0; j < 4; j++) {
            pw0[i][j] = pk2(s[i][j][0], s[i][j][1]);
            pw1[i][j] = pk2(s[i][j][2], s[i][j][3]);
        }
    f32x4 o[4][2];
    #pragma unroll
    for (int i = 0; i < 4; i++) { o[i][0] = (f32x4){0,0,0,0}; o[i][1] = (f32x4){0,0,0,0}; }
    #pragma unroll
    for (int ks = 0; ks < 2; ks++) {
        bf16x8 pa[4], vb[2];
        #pragma unroll
        for (int i = 0; i < 4; i++) {
            unsigned a0 = __shfl(pw0[i][2 * ks], srcA), b0 = __shfl(pw0[i][2 * ks + 1], srcA);
            unsigned a1 = __shfl(pw1[i][2 * ks], srcA), b1 = __shfl(pw1[i][2 * ks + 1], srcA);
            unsigned a2 = __shfl(pw0[i][2 * ks], srcB), b2 = __shfl(pw0[i][2 * ks + 1], srcB);
            unsigned a3 = __shfl(pw1[i][2 * ks], srcB), b3 = __shfl(pw1[i][2 * ks + 1], srcB);
            union { uint4 u; bf16x8 v; } cv;
            cv.u.x = nhi ? b0 : a0;
            cv.u.y = nhi ? b1 : a1;
            cv.u.z = nhi ? b2 : a2;
            cv.u.w = nhi ? b3 : a3;
            pa[i] = cv.v;
        }
        #pragma unroll
        for (int j = 0; j < 2; j++) {
            int d = j * 16 + c;
            vb[j] = *(const bf16x8*)(vt + d * 80 + ks * 32 + 8 * g);
        }
        #pragma unroll
        for (int i = 0; i < 4; i++)
            #pragma unroll
            for (int j = 0; j < 2; j++)
                o[i][j] = __builtin_amdgcn_mfma_f32_16x16x32_bf16(vb[j], pa[i], o[i][j], 0, 0, 0);
    }

    // O -> Olds
    #pragma unroll
    for (int i = 0; i < 4; i++) {
        int row = i * 16 + c;
        #pragma unroll
        for (int j = 0; j < 2; j++) {
            uint2 pk = { pk2(o[i][j][0], o[i][j][1]), pk2(o[i][j][2], o[i][j][3]) };
            *(uint2*)((char*)Olds + row * XROW + w * 64 + j * 32 + g * 8) = pk;
        }
    }
    __syncthreads();   // bar3: all heads' O in Olds; all Vt reads done

    // proj: wave w -> out cols w*32..+32, K=256 from Olds (weight dbuf)
    f32x4 ap[4][2];
    #pragma unroll
    for (int i = 0; i < 4; i++) { ap[i][0] = (f32x4){0,0,0,0}; ap[i][1] = (f32x4){0,0,0,0}; }
    {
        bf16x8 wcur[2], wnxt[2];
        #pragma unroll
        for (int n = 0; n < 2; n++)
            wcur[n] = pp[(size_t)((w * 2 + n) * 8 + 0) * 64 + lane];
        #pragma unroll
        for (int ks = 0; ks < 8; ks++) {
            if (ks + 1 < 8) {
                #pragma unroll
                for (int n = 0; n < 2; n++)
                    wnxt[n] = pp[(size_t)((w * 2 + n) * 8 + ks + 1) * 64 + lane];
            }
            bf16x8 ah[4];
            #pragma unroll
            for (int i = 0; i < 4; i++)
                ah[i] = *(const bf16x8*)((char*)Olds + (i * 16 + c) * XROW
                                         + g * 16 + ks * 64);
            __builtin_amdgcn_s_setprio(1);
            #pragma unroll
            for (int i = 0; i < 4; i++)
                #pragma unroll
                for (int n = 0; n < 2; n++)
                    ap[i][n] = __builtin_amdgcn_mfma_f32_16x16x32_bf16(
                        wcur[n], ah[i], ap[i][n], 0, 0, 0);
            __builtin_amdgcn_s_setprio(0);
            #pragma unroll
            for (int n = 0; n < 2; n++) wcur[n] = wnxt[n];
        }
    }

    // x = proj + p_b + f32 residual -> bf16 packed regs, and write Xl4
    uint2 xs[4][2];
    #pragma unroll
    for (int i = 0; i < 4; i++) {
        int n = i * 16 + c;
        size_t nrow = (size_t)b_ * 4096 + (wh * 8 + (n >> 3)) * 64 + ww * 8 + (n & 7);
        #pragma unroll
        for (int j = 0; j < 2; j++) {
            int col = w * 32 + j * 16 + 4 * g;
            float4 b4 = *(const float4*)(p_b + col);
            float4 r4 = *(const float4*)(x1 + nrow * 256 + col);
            uint2 pk = { pk2(ap[i][j][0] + b4.x + r4.x, ap[i][j][1] + b4.y + r4.y),
                         pk2(ap[i][j][2] + b4.z + r4.z, ap[i][j][3] + b4.w + r4.w) };
            xs[i][j] = pk;
            *(uint2*)((char*)Xl4 + (i * 16 + c) * XROW + w * 64 + j * 32 + g * 8) = pk;
        }
    }
    __syncthreads();   // bar4: full x in Xl4; all Olds reads done

    // ---- phase 4a: LN3 in place on Xl4 (16-lane groups, 2 iters) ----
    {
        const int ln_sub = lane >> 4, ln_c = lane & 15;
        float4 G3[4], B3[4];
        #pragma unroll
        for (int j = 0; j < 4; j++) {
            G3[j] = *(const float4*)(n3g + ln_c * 16 + j * 4);
            B3[j] = *(const float4*)(n3b + ln_c * 16 + j * 4);
        }
        const float* G = (const float*)G3;
        const float* B = (const float*)B3;
        #pragma unroll
        for (int it = 0; it < 2; it++) {
            int row = w * 8 + it * 4 + ln_sub;
            char* base = (char*)Xl4 + row * XROW + ln_c * 32;
            uint4 rv = *(const uint4*)(base);
            uint4 rw = *(const uint4*)(base + 16);
            float v[16];
            v[0] = bf2f((u16)rv.x);  v[1] = bf2f((u16)(rv.x >> 16));
            v[2] = bf2f((u16)rv.y);  v[3] = bf2f((u16)(rv.y >> 16));
            v[4] = bf2f((u16)rv.z);  v[5] = bf2f((u16)(rv.z >> 16));
            v[6] = bf2f((u16)rv.w);  v[7] = bf2f((u16)(rv.w >> 16));
            v[8] = bf2f((u16)rw.x);  v[9] = bf2f((u16)(rw.x >> 16));
            v[10] = bf2f((u16)rw.y); v[11] = bf2f((u16)(rw.y >> 16));
            v[12] = bf2f((u16)rw.z); v[13] = bf2f((u16)(rw.z >> 16));
            v[14] = bf2f((u16)rw.w); v[15] = bf2f((u16)(rw.w >> 16));
            float sm = 0.f, qm = 0.f;
            #pragma unroll
            for (int e = 0; e < 16; e++) { sm += v[e]; qm += v[e] * v[e]; }
            #pragma unroll
            for (int m_ = 1; m_ <= 8; m_ <<= 1) {
                sm += __shfl_xor(sm, m_, 64);
                qm += __shfl_xor(qm, m_, 64);
            }
            float mean = sm * (1.0f / 256.0f);
            float rstd = rsqrtf(qm * (1.0f / 256.0f) - mean * mean + 1e-5f);
            uint4 o0, o1;
            o0.x = pk2((v[0]-mean)*rstd*G[0]+B[0],  (v[1]-mean)*rstd*G[1]+B[1]);
            o0.y = pk2((v[2]-mean)*rstd*G[2]+B[2],  (v[3]-mean)*rstd*G[3]+B[3]);
            o0.z = pk2((v[4]-mean)*rstd*G[4]+B[4],  (v[5]-mean)*rstd*G[5]+B[5]);
            o0.w = pk2((v[6]-mean)*rstd*G[6]+B[6],  (v[7]-mean)*rstd*G[7]+B[7]);
            o1.x = pk2((v[8]-mean)*rstd*G[8]+B[8],  (v[9]-mean)*rstd*G[9]+B[9]);
            o1.y = pk2((v[10]-mean)*rstd*G[10]+B[10],(v[11]-mean)*rstd*G[11]+B[11]);
            o1.z = pk2((v[12]-mean)*rstd*G[12]+B[12],(v[13]-mean)*rstd*G[13]+B[13]);
            o1.w = pk2((v[14]-mean)*rstd*G[14]+B[14],(v[15]-mean)*rstd*G[15]+B[15]);
            *(uint4*)(base) = o0;
            *(uint4*)(base + 16) = o1;
        }
    }
    __syncthreads();   // bar5: LN3(x) in Xl4

    // ---- phase 4b: MLP (fc1+gelu -> Hl4; fc2 accumulate) ----
    f32x4 acc2[4][2];
    #pragma unroll
    for (int i = 0; i < 4; i++) { acc2[i][0] = (f32x4){0,0,0,0}; acc2[i][1] = (f32x4){0,0,0,0}; }

    #pragma unroll
    for (int hc = 0; hc < 4; hc++) {
        f32x4 acc1[4][2];
        #pragma unroll
        for (int i = 0; i < 4; i++) { acc1[i][0] = (f32x4){0,0,0,0}; acc1[i][1] = (f32x4){0,0,0,0}; }

        const bf16x8* f1base = f1p + (size_t)((hc * 16 + w * 2) * 8) * 64 + lane;
        bf16x8 wA[2], wB[2];
        #pragma unroll
        for (int n = 0; n < 2; n++) wA[n] = f1base[(n * 8 + 0) * 64];

#define FC1_STEP(WREG, ks_)                                                   \
        {                                                                     \
            bf16x8 af[4];                                                     \
            _Pragma("unroll")                                                 \
            for (int i = 0; i < 4; i++)                                       \
                af[i] = *(const bf16x8*)((char*)Xl4 + (i * 16 + c) * XROW     \
                                         + g * 16 + (ks_) * 64);             \
            __builtin_amdgcn_s_setprio(1);                                    \
            _Pragma("unroll")                                                 \
            for (int i = 0; i < 4; i++)                                       \
                _Pragma("unroll")                                             \
                for (int n = 0; n < 2; n++)                                   \
                    acc1[i][n] = __builtin_amdgcn_mfma_f32_16x16x32_bf16(     \
                        WREG[n], af[i], acc1[i][n], 0, 0, 0);                 \
            __builtin_amdgcn_s_setprio(0);                                    \
        }

        #pragma unroll
        for (int ks = 0; ks < 8; ks += 2) {
            #pragma unroll
            for (int n = 0; n < 2; n++) wB[n] = f1base[(n * 8 + ks + 1) * 64];
            FC1_STEP(wA, ks)
            if (ks + 2 < 8) {
                #pragma unroll
                for (int n = 0; n < 2; n++) wA[n] = f1base[(n * 8 + ks + 2) * 64];
            }
            FC1_STEP(wB, ks + 1)
        }
#undef FC1_STEP

        #pragma unroll
        for (int i = 0; i < 4; i++) {
            int row = i * 16 + c;
            #pragma unroll
            for (int n = 0; n < 2; n++) {
                float4 b4 = *(const float4*)(f1b + hc * 256 + w * 32 + n * 16 + 4 * g);
                float h0 = gelu_s(acc1[i][n][0] + b4.x);
                float h1 = gelu_s(acc1[i][n][1] + b4.y);
                float h2 = gelu_s(acc1[i][n][2] + b4.z);
                float h3 = gelu_s(acc1[i][n][3] + b4.w);
                uint2 pk = { pk2(h0, h1), pk2(h2, h3) };
                *(uint2*)((char*)Hl4 + row * XROW + w * 64 + n * 32 + g * 8) = pk;
            }
        }
        __syncthreads();

        const bf16x8* f2base = f2p + (size_t)((w * 2) * 32 + hc * 8) * 64 + lane;
        #pragma unroll
        for (int n = 0; n < 2; n++) wA[n] = f2base[(n * 32 + 0) * 64];

#define FC2_STEP(WREG, ks_)                                                   \
        {                                                                     \
            bf16x8 ah[4];                                                     \
            _Pragma("unroll")                                                 \
            for (int i = 0; i < 4; i++)                                       \
                ah[i] = *(const bf16x8*)((char*)Hl4 + (i * 16 + c) * XROW     \
                                         + g * 16 + (ks_) * 64);             \
            __builtin_amdgcn_s_setprio(1);                                    \
            _Pragma("unroll")                                                 \
            for (int i = 0; i < 4; i++)                                       \
                _Pragma("unroll")                                             \
                for (int n = 0; n < 2; n++)                                   \
                    acc2[i][n] = __builtin_amdgcn_mfma_f32_16x16x32_bf16(     \
                        WREG[n], ah[i], acc2[i][n], 0, 0, 0);                 \
            __builtin_amdgcn_s_setprio(0);                                    \
        }

        #pragma unroll
        for (int ks = 0; ks < 8; ks += 2) {
            #pragma unroll
            for (int n = 0; n < 2; n++) wB[n] = f2base[(n * 32 + ks + 1) * 64];
            FC2_STEP(wA, ks)
            if (ks + 2 < 8) {
                #pragma unroll
                for (int n = 0; n < 2; n++) wA[n] = f2base[(n * 32 + ks + 2) * 64];
            }
            FC2_STEP(wB, ks + 1)
        }
#undef FC2_STEP
        __syncthreads();
    }

    // ---- epilogue: stage f32 rows in Fb; each WAVE writes one full 1KB
    //      row per store (lane*4 contiguous) -> zero partial cache lines ----
    {
        float* Fb = (float*)SMEM;    // entire arena dead after last barrier
        #pragma unroll
        for (int i = 0; i < 4; i++) {
            int row = i * 16 + c;
            #pragma unroll
            for (int j = 0; j < 2; j++) {
                int coloff = w * 32 + j * 16 + 4 * g;
                float4 b4 = *(const float4*)(f2b + coloff);
                uint2 rr2 = xs[i][j];
                f32x4 ov = { acc2[i][j][0] + b4.x + bf2f((u16)rr2.x),
                             acc2[i][j][1] + b4.y + bf2f((u16)(rr2.x >> 16)),
                             acc2[i][j][2] + b4.z + bf2f((u16)rr2.y),
                             acc2[i][j][3] + b4.w + bf2f((u16)(rr2.y >> 16)) };
                *(f32x4*)(Fb + row * FROW + coloff) = ov;
            }
        }
        __syncthreads();
        #pragma unroll
        for (int it = 0; it < 8; it++) {
            int n = w * 8 + it;
            size_t nrow = (size_t)b_ * 4096 + (wh * 8 + (n >> 3)) * 64 + ww * 8 + (n & 7);
            float4 a = *(const float4*)(Fb + n * FROW + lane * 4);
            *(float4*)(out + nrow * 256 + lane * 4) = a;
        }
    }
#undef GEMM256
#undef ADDBIAS
#undef REPACK
}

// -------------------------------------------------------------- launch ------
// Workspace (peak ~2.1 MB): weights only.
extern "C" void kernel_launch(void* const* d_in, const int* in_sizes, int n_in,
                              void* d_out, int out_size, void* d_ws, size_t ws_size,
                              hipStream_t stream)
{
    const float* x1  = (const float*)d_in[0];
    const float* x2  = (const float*)d_in[1];
    const float* n1g = (const float*)d_in[2];
    const float* n1b = (const float*)d_in[3];
    const float* q_w = (const float*)d_in[4];
    const float* q_b = (const float*)d_in[5];
    const float* kv_w= (const float*)d_in[6];
    const float* kv_b= (const float*)d_in[7];
    const float* p_w = (const float*)d_in[8];
    const float* p_b = (const float*)d_in[9];
    const float* rel = (const float*)d_in[10];
    const float* n3g = (const float*)d_in[11];
    const float* n3b = (const float*)d_in[12];
    const float* f1w = (const float*)d_in[13];
    const float* f1b = (const float*)d_in[14];
    const float* f2w = (const float*)d_in[15];
    const float* f2b = (const float*)d_in[16];

    char* ws = (char*)d_ws;
    u16*   qp    = (u16*)(ws + 0);
    u16*   kvp   = (u16*)(ws + 131072);
    u16*   pp    = (u16*)(ws + 393216);
    u16*   f1p   = (u16*)(ws + 524288);
    u16*   f2p   = (u16*)(ws + 1048576);
    float* biasF = (float*)(ws + 1572864);

    float* out = (float*)d_out;

    prep_k<<<3200, 256, 0, stream>>>(q_w, kv_w, p_w, f1w, f2w, rel,
                                     qp, kvp, pp, f1p, f2p, biasF);
    block_mega<<<1024, 512, 0, stream>>>(x1, x2, n1g, n1b, (const bf16x8*)qp,
                                         (const bf16x8*)kvp, q_b, kv_b, biasF,
                                         (const bf16x8*)pp, p_b, n3g, n3b,
                                         (const bf16x8*)f1p, (const bf16x8*)f2p,
                                         f1b, f2b, out);
}